// Round 2
// baseline (314.049 us; speedup 1.0000x reference)
//
#include <hip/hip_runtime.h>
#include <stdint.h>

// Problem constants (B=2, Lq=Lk=2048, E=1024, H=16, Dh=64).
// Inputs/outputs are FLOAT32 (per reference); MFMA compute runs in bf16
// after an explicit f32->bf16 conversion pass into workspace.
#define B_   2
#define SEQ  2048
#define EMB  1024
#define NH   16
#define DH   64
#define BIGF 1e10f
#define PST  72   // padded LDS row stride (elems) for P/Vt: 144B = 16B-aligned, 2-way banks (free)

typedef unsigned short u16;
typedef __attribute__((ext_vector_type(8))) short    bf8;   // 8 x bf16 (4 VGPRs) MFMA frag
typedef __attribute__((ext_vector_type(4))) float    f4;    // MFMA accum frag
typedef __attribute__((ext_vector_type(4))) float    fv4;   // 16B f32 vector load
typedef __attribute__((ext_vector_type(4))) uint32_t u32x4; // 16B vector load

__device__ inline float bf2f(u16 u){ union{uint32_t i; float f;} v; v.i = ((uint32_t)u) << 16; return v.f; }
__device__ inline u16 f2bf(float f){ union{float f; uint32_t i;} v; v.f = f;
                                     uint32_t r = v.i + 0x7fffu + ((v.i >> 16) & 1u); return (u16)(r >> 16); }

// async global->LDS, 16B per lane; LDS dest is wave-uniform base + lane*16
__device__ inline void gl_lds16(const void* g, void* l){
  __builtin_amdgcn_global_load_lds((const __attribute__((address_space(1))) uint32_t*)g,
                                   (__attribute__((address_space(3))) uint32_t*)l, 16, 0, 0);
}

// ---------------- f32 -> bf16 conversion (6 segments), 8 elems/thread
struct CvtArgs { const float* src[6]; u16* dst[6]; int n[6]; };

__global__ __launch_bounds__(256) void cvt_bf16(CvtArgs a)
{
  const int seg = blockIdx.y;
  const float* __restrict__ s = a.src[seg];
  u16* __restrict__ d = a.dst[seg];
  const int n = a.n[seg];
  const int i = (blockIdx.x * 256 + threadIdx.x) * 8;
  if (i >= n) return;
  fv4 x0 = *(const fv4*)(s + i);
  fv4 x1 = *(const fv4*)(s + i + 4);
  union { bf8 v; u16 u[8]; } o;
#pragma unroll
  for (int j = 0; j < 4; j++) { o.u[j] = f2bf(x0[j]); o.u[4 + j] = f2bf(x1[j]); }
  *(bf8*)(d + i) = o.v;
}

// ---------------- Projection GEMM: Y[l,e] = sum_d X[l,d] * W[e,d]  (NT, bf16->bf16, f32 accum)
// M=4096 (B*SEQ), N=1024, K=1024. 128x128 tile, BK=32, 256 threads, wave computes 64x64.
__global__ __launch_bounds__(256) void proj_gemm(
    const u16* __restrict__ Xq, const u16* __restrict__ Xk, const u16* __restrict__ Xv,
    const u16* __restrict__ Wq, const u16* __restrict__ Wk, const u16* __restrict__ Wv,
    u16* __restrict__ Yq, u16* __restrict__ Yk, u16* __restrict__ Yv)
{
  __shared__ u16 lA[128 * 32];
  __shared__ u16 lB[128 * 32];
  const int z = blockIdx.z;
  const u16* X = (z == 0) ? Xq : ((z == 1) ? Xk : Xv);
  const u16* W = (z == 0) ? Wq : ((z == 1) ? Wk : Wv);
  u16*       Y = (z == 0) ? Yq : ((z == 1) ? Yk : Yv);

  const int tid  = threadIdx.x;
  const int lane = tid & 63;
  const int w    = tid >> 6;
  const int wm   = w >> 1, wn = w & 1;
  const int m0   = blockIdx.x * 128;
  const int n0   = blockIdx.y * 128;

  const f4 zero = {0.f, 0.f, 0.f, 0.f};
  f4 acc[4][4];
#pragma unroll
  for (int i = 0; i < 4; i++)
#pragma unroll
    for (int j = 0; j < 4; j++) acc[i][j] = zero;

  for (int k0 = 0; k0 < 1024; k0 += 32) {
    __syncthreads();
#pragma unroll
    for (int j = 0; j < 2; j++) {
      const int c = j * 256 + tid;              // 16B chunk index; 4 chunks per 32-elem row
      const int row = c >> 2, cc = (c & 3) * 8;
      gl_lds16(X + (size_t)(m0 + row) * 1024 + k0 + cc, &lA[(j * 256 + w * 64) * 8]);
      gl_lds16(W + (size_t)(n0 + row) * 1024 + k0 + cc, &lB[(j * 256 + w * 64) * 8]);
    }
    __syncthreads();
    const int koff = (lane >> 4) * 8;
    bf8 a[4], b[4];
#pragma unroll
    for (int t = 0; t < 4; t++) a[t] = *(const bf8*)&lA[(wm * 64 + t * 16 + (lane & 15)) * 32 + koff];
#pragma unroll
    for (int t = 0; t < 4; t++) b[t] = *(const bf8*)&lB[(wn * 64 + t * 16 + (lane & 15)) * 32 + koff];
#pragma unroll
    for (int mt = 0; mt < 4; mt++)
#pragma unroll
      for (int nt = 0; nt < 4; nt++)
        acc[mt][nt] = __builtin_amdgcn_mfma_f32_16x16x32_bf16(a[mt], b[nt], acc[mt][nt], 0, 0, 0);
  }

  const int col = lane & 15, quad = lane >> 4;   // C/D: col=lane&15, row=quad*4+r
#pragma unroll
  for (int mt = 0; mt < 4; mt++)
#pragma unroll
    for (int nt = 0; nt < 4; nt++)
#pragma unroll
      for (int r = 0; r < 4; r++) {
        const int m = m0 + wm * 64 + mt * 16 + quad * 4 + r;
        const int n = n0 + wn * 64 + nt * 16 + col;
        Y[(size_t)m * 1024 + n] = f2bf(acc[mt][nt][r]);
      }
}

// ---------------- Flash-style attention with exact reference mask semantics.
// Block = (q-tile of 64, head, batch); 4 waves x 16 q-rows. Full sweep over all 32 K-tiles
// (reference applies BIG penalties, doesn't skip — dead rows need the -1e10 entries).
__global__ __launch_bounds__(256) void attn(
    const u16* __restrict__ QW, const u16* __restrict__ KW, const u16* __restrict__ VW,
    const float* __restrict__ vmask, const float* __restrict__ qmask,
    float* __restrict__ OUT)
{
  __shared__ float pen[SEQ];        // (1 - v_mask[k]) * 1e10, f32
  __shared__ u16   Vt[64 * PST];    // V tile transposed: [d][key]
  __shared__ u16   P [64 * PST];    // exp(S - m) tile: [q_local][key], wave-private rows

  const int tid = threadIdx.x, lane = tid & 63, w = tid >> 6;
  const int b = blockIdx.z, h = blockIdx.y;
  const int q0 = blockIdx.x * 64;
  const int col = lane & 15, quad = lane >> 4;

  for (int i = tid; i < SEQ; i += 256)
    pen[i] = (1.0f - vmask[b * SEQ + i]) * BIGF;

  // Q A-frags held in registers across all K-tiles: A[m=lane&15][k=quad*8+j]
  const int qa = q0 + w * 16 + col;
  bf8 aQ[2];
#pragma unroll
  for (int dh = 0; dh < 2; dh++)
    aQ[dh] = *(const bf8*)&QW[(size_t)(b * SEQ + qa) * EMB + h * 64 + dh * 32 + quad * 8];

  const f4 zero = {0.f, 0.f, 0.f, 0.f};
  float m_i[4], l_i[4];
  f4 accO[4];
#pragma unroll
  for (int r = 0; r < 4; r++) { m_i[r] = -INFINITY; l_i[r] = 0.f; }
#pragma unroll
  for (int t = 0; t < 4; t++) accO[t] = zero;

  __syncthreads();  // pen ready

  for (int kt = 0; kt < 32; kt++) {
    const int k0 = kt * 64;

    // V tile -> regs (wave w holds d-cols w*16..w*16+15 of key row `lane`)
    union { u32x4 v4[2]; u16 u[16]; } vbuf;
    {
      const u16* vp = &VW[(size_t)(b * SEQ + k0 + lane) * EMB + h * 64 + w * 16];
      vbuf.v4[0] = *(const u32x4*)vp;
      vbuf.v4[1] = *(const u32x4*)(vp + 8);
    }

    // S = Q K^T : B-frags of K straight from global (L1 serves 4-wave reuse)
    f4 accS[4];
#pragma unroll
    for (int t = 0; t < 4; t++) accS[t] = zero;
#pragma unroll
    for (int nt = 0; nt < 4; nt++) {
      const int key = k0 + nt * 16 + col;       // B-frag n = lane&15
      const u16* kp = &KW[(size_t)(b * SEQ + key) * EMB + h * 64 + quad * 8];
#pragma unroll
      for (int dh = 0; dh < 2; dh++) {
        bf8 bK = *(const bf8*)(kp + dh * 32);
        accS[nt] = __builtin_amdgcn_mfma_f32_16x16x32_bf16(aQ[dh], bK, accS[nt], 0, 0, 0);
      }
    }

    // masks (exact f32 order: s/8 - keypad - causal) + online softmax
    float s[4][4], pmax[4];
#pragma unroll
    for (int r = 0; r < 4; r++) {
      const int qr = q0 + w * 16 + quad * 4 + r;  // C/D row = quad*4+r
      float mx = -INFINITY;
#pragma unroll
      for (int nt = 0; nt < 4; nt++) {
        const int key = k0 + nt * 16 + col;
        float sv = accS[nt][r] * 0.125f - pen[key];
        if (key <= qr) sv -= BIGF;                // tril INCLUDING diagonal penalized
        s[nt][r] = sv;
        mx = fmaxf(mx, sv);
      }
      pmax[r] = mx;
    }
#pragma unroll
    for (int r = 0; r < 4; r++) {
      float x = pmax[r];
      x = fmaxf(x, __shfl_xor(x, 1));
      x = fmaxf(x, __shfl_xor(x, 2));
      x = fmaxf(x, __shfl_xor(x, 4));
      x = fmaxf(x, __shfl_xor(x, 8));
      pmax[r] = x;
    }
    float alpha[4];
#pragma unroll
    for (int r = 0; r < 4; r++) {
      const float mnew = fmaxf(m_i[r], pmax[r]);
      alpha[r] = __expf(m_i[r] - mnew);           // exp(0)=1 exact; exp(-1e10)=0
      m_i[r] = mnew;
      float sum = 0.f;
#pragma unroll
      for (int nt = 0; nt < 4; nt++) {
        const float p = __expf(s[nt][r] - mnew);
        s[nt][r] = p;
        sum += p;
      }
      float x = sum;
      x += __shfl_xor(x, 1);
      x += __shfl_xor(x, 2);
      x += __shfl_xor(x, 4);
      x += __shfl_xor(x, 8);
      l_i[r] = l_i[r] * alpha[r] + x;
    }
#pragma unroll
    for (int t = 0; t < 4; t++)
#pragma unroll
      for (int r = 0; r < 4; r++)
        accO[t][r] *= alpha[r];

    __syncthreads();   // all waves done reading Vt/P of previous tile
    // V transposed into LDS: per j, 64 lanes write one 128B-contiguous row -> conflict-free
#pragma unroll
    for (int j = 0; j < 16; j++)
      Vt[(w * 16 + j) * PST + lane] = vbuf.u[j];
    // P (C-layout -> memory [q][key]); wave-private rows
#pragma unroll
    for (int nt = 0; nt < 4; nt++)
#pragma unroll
      for (int r = 0; r < 4; r++)
        P[(w * 16 + quad * 4 + r) * PST + nt * 16 + col] = f2bf(s[nt][r]);
    __syncthreads();   // Vt/P visible

    // O += P V : A = P[m=q][k=key], B = Vt[n=d][k=key]
#pragma unroll
    for (int kk = 0; kk < 2; kk++) {
      bf8 aP = *(const bf8*)&P[(w * 16 + col) * PST + kk * 32 + quad * 8];
#pragma unroll
      for (int nt = 0; nt < 4; nt++) {
        bf8 bV = *(const bf8*)&Vt[(nt * 16 + col) * PST + kk * 32 + quad * 8];
        accO[nt] = __builtin_amdgcn_mfma_f32_16x16x32_bf16(aP, bV, accO[nt], 0, 0, 0);
      }
    }
  }

  // epilogue: divide by l, apply q_mask, store f32
#pragma unroll
  for (int r = 0; r < 4; r++) {
    const int q = q0 + w * 16 + quad * 4 + r;
    const float qm = qmask[b * SEQ + q];
    const float invl = 1.0f / l_i[r];             // l >= 1 always (max entry has p=1)
#pragma unroll
    for (int nt = 0; nt < 4; nt++) {
      const float o = accO[nt][r] * invl * qm;
      OUT[(size_t)(b * SEQ + q) * EMB + h * 64 + nt * 16 + col] = o;
    }
  }
}

extern "C" void kernel_launch(void* const* d_in, const int* in_sizes, int n_in,
                              void* d_out, int out_size, void* d_ws, size_t ws_size,
                              hipStream_t stream)
{
  const float* q  = (const float*)d_in[0];
  const float* k  = (const float*)d_in[1];
  const float* v  = (const float*)d_in[2];
  const float* vm = (const float*)d_in[3];
  const float* qm = (const float*)d_in[4];
  const float* Wq = (const float*)d_in[5];
  const float* Wk = (const float*)d_in[6];
  const float* Wv = (const float*)d_in[7];
  float* out = (float*)d_out;

  const size_t NBIG = (size_t)B_ * SEQ * EMB;   // 4 Mi elems
  const size_t NW   = (size_t)EMB * EMB;        // 1 Mi elems

  // workspace (u16 elems): qb,kb,vb (4Mi ea) | Wqb,Wkb,Wvb (1Mi ea) | qw,kw,vw (4Mi ea)
  u16* qb  = (u16*)d_ws;
  u16* kb  = qb  + NBIG;
  u16* vb  = kb  + NBIG;
  u16* Wqb = vb  + NBIG;
  u16* Wkb = Wqb + NW;
  u16* Wvb = Wkb + NW;
  u16* qw  = Wvb + NW;
  u16* kw  = qw  + NBIG;
  u16* vw  = kw  + NBIG;

  CvtArgs ca;
  ca.src[0] = q;  ca.dst[0] = qb;  ca.n[0] = (int)NBIG;
  ca.src[1] = k;  ca.dst[1] = kb;  ca.n[1] = (int)NBIG;
  ca.src[2] = v;  ca.dst[2] = vb;  ca.n[2] = (int)NBIG;
  ca.src[3] = Wq; ca.dst[3] = Wqb; ca.n[3] = (int)NW;
  ca.src[4] = Wk; ca.dst[4] = Wkb; ca.n[4] = (int)NW;
  ca.src[5] = Wv; ca.dst[5] = Wvb; ca.n[5] = (int)NW;

  cvt_bf16<<<dim3((unsigned)(NBIG / 8 / 256), 6, 1), 256, 0, stream>>>(ca);
  proj_gemm<<<dim3(32, 8, 3), 256, 0, stream>>>(qb, kb, vb, Wqb, Wkb, Wvb, qw, kw, vw);
  attn<<<dim3(SEQ / 64, NH, B_), 256, 0, stream>>>(qw, kw, vw, vm, qm, out);
}